// Round 2
// baseline (799.707 us; speedup 1.0000x reference)
//
#include <hip/hip_runtime.h>
#include <hip/hip_bf16.h>
#include <stdint.h>

// FMoENaiveGate on MI355X (gfx950).
// gate = inp[16384,4096] @ W[128,4096]^T + b ; top-2 + softmax, fused.
// fp32 emulated via 4-product bf16 hi/lo split MFMA (~2.5 PF pipe); rows whose
// top-3 gate gaps are < 1e-3 are re-scored exactly in fp32 by a fixup kernel
// (expected ~80 rows), so final indices are fp32-grade.

typedef __attribute__((ext_vector_type(8))) short  short8;   // bf16x8 frag (4 VGPR)
typedef __attribute__((ext_vector_type(4))) float  f32x4;

typedef __attribute__((address_space(1))) unsigned int GU;   // global
typedef __attribute__((address_space(3))) unsigned int LU;   // LDS

#define MFMA16(a, b, c) __builtin_amdgcn_mfma_f32_16x16x32_bf16((a), (b), (c), 0, 0, 0)

#define N_TOK 16384
#define N_DIM 4096
#define N_EXP 128
#define GAP_THR 1.0e-3f

// ---- fp32 -> bf16 RNE, and hi/lo split ------------------------------------
__device__ __forceinline__ unsigned short f2bf(float f) {
  uint32_t u = __float_as_uint(f);
  u += 0x7fffu + ((u >> 16) & 1u);          // round-nearest-even
  return (unsigned short)(u >> 16);
}
__device__ __forceinline__ void split2(float x, short& h, short& l) {
  unsigned short hb = f2bf(x);
  float hf = __uint_as_float(((uint32_t)hb) << 16);
  l = (short)f2bf(x - hf);                  // x - hf exact (Sterbenz)
  h = (short)hb;
}
__device__ __forceinline__ void cvt8(const f32x4& a, const f32x4& b, short8& h8, short8& l8) {
#pragma unroll
  for (int i = 0; i < 4; ++i) { short h, l; split2(a[i], h, l); h8[i] = h; l8[i] = l; }
#pragma unroll
  for (int i = 0; i < 4; ++i) { short h, l; split2(b[i], h, l); h8[4 + i] = h; l8[4 + i] = l; }
}

// top-2 merge with jax.lax.top_k tie rule (lower index wins on equal value)
__device__ __forceinline__ void merge2(float& v1, int& i1, float& v2, int& i2,
                                       float pv1, int pi1, float pv2, int pi2) {
  if (pv1 > v1 || (pv1 == v1 && pi1 < i1)) { v2 = v1; i2 = i1; v1 = pv1; i1 = pi1; }
  else if (pv1 > v2 || (pv1 == v2 && pi1 < i2)) { v2 = pv1; i2 = pi1; }
  if (pv2 > v1 || (pv2 == v1 && pi2 < i1)) { v2 = v1; i2 = i1; v1 = pv2; i1 = pi2; }
  else if (pv2 > v2 || (pv2 == v2 && pi2 < i2)) { v2 = pv2; i2 = pi2; }
}

// ---- Kernel 1: W [128][4096] f32 -> Whi/Wlo bf16 --------------------------
__global__ __launch_bounds__(256) void wsplit_kernel(const float* __restrict__ W,
                                                     unsigned short* __restrict__ Whi,
                                                     unsigned short* __restrict__ Wlo) {
  int g = blockIdx.x * 256 + threadIdx.x;           // 65536 threads, 8 elems each
  int base = g * 8;
  f32x4 v0 = *reinterpret_cast<const f32x4*>(W + base);
  f32x4 v1 = *reinterpret_cast<const f32x4*>(W + base + 4);
  short8 h8, l8;
  cvt8(v0, v1, h8, l8);
  *reinterpret_cast<short8*>(Whi + base) = h8;
  *reinterpret_cast<short8*>(Wlo + base) = l8;
}

// ---- Kernel 2: fused split-GEMM + bias + top2 + softmax + gap flag --------
// BM=64, BN=128 (all experts), BK=64. 512 thr / 8 waves (2M x 4N), wave tile 32x32.
// LDS per buffer (48 KB): sA_hi[64][64] @0, sA_lo @8192, sB_hi[128][64] @16384,
// sB_lo @32768; double-buffered -> 96 KB dynamic LDS.
// Swizzle: 16B chunk c of row r stored at chunk c ^ (r&7)  (involution; same
// formula pre-applied to global_load_lds source, rule #21).
__global__ __launch_bounds__(512) void gate_topk_kernel(const float* __restrict__ A,
                                                        const unsigned short* __restrict__ Whi,
                                                        const unsigned short* __restrict__ Wlo,
                                                        const float* __restrict__ bias,
                                                        float* __restrict__ out,
                                                        unsigned int* __restrict__ flags) {
  extern __shared__ char sm[];
  const int tid  = threadIdx.x;
  const int lane = tid & 63;
  const int wv   = tid >> 6;        // 0..7
  const int wrow = wv >> 2;         // 0..1  (M)
  const int wcol = wv & 3;          // 0..3  (N)
  const int fr   = lane & 15;
  const int kg   = lane >> 4;       // 0..3
  const int rb   = blockIdx.x * 64; // block row base (grid=256)

  f32x4 acc[2][2];
#pragma unroll
  for (int m = 0; m < 2; ++m)
#pragma unroll
    for (int n = 0; n < 2; ++n) acc[m][n] = (f32x4){0.f, 0.f, 0.f, 0.f};

  // A staging: thread owns row rA, 8 fp32 at col cA*8 per K-tile
  const int rA = tid >> 3, cA = tid & 7;
  const float* gA = A + (size_t)(rb + rA) * N_DIM + cA * 8;
  const int wAoff = rA * 128 + ((cA ^ (rA & 7)) * 16);   // swizzled 16B chunk

  // B staging via global_load_lds: linear LDS slot s -> phys chunk (s&7) of row
  // (s>>3); source chunk = (s&7) ^ (row&7) so that LDS holds swizzled layout.
  int sBoff[2];
#pragma unroll
  for (int p = 0; p < 2; ++p) {
    int s = p * 512 + tid;
    int rW = s >> 3, pc = s & 7;
    sBoff[p] = rW * N_DIM + ((pc ^ (rW & 7)) * 8);       // elements
  }

  auto stageB = [&](int bufO, int ktn) {
#pragma unroll
    for (int p = 0; p < 2; ++p) {
      const unsigned short* gh = Whi + sBoff[p] + ktn * 64;
      const unsigned short* gl = Wlo + sBoff[p] + ktn * 64;
      char* lbh = sm + bufO + 16384 + (p * 512 + wv * 64) * 16;  // wave-uniform
      char* lbl = sm + bufO + 32768 + (p * 512 + wv * 64) * 16;
      __builtin_amdgcn_global_load_lds((const GU*)gh, (LU*)lbh, 16, 0, 0);
      __builtin_amdgcn_global_load_lds((const GU*)gl, (LU*)lbl, 16, 0, 0);
    }
  };

  // per-wave fragment rows (row&7 == fr&7 for all m/n since tiles are 16-aligned)
  const int rowA0 = (wrow * 32 + fr) * 128;
  const int rowA1 = rowA0 + 16 * 128;
  const int rowB0 = (wcol * 32 + fr) * 128;
  const int rowB1 = rowB0 + 16 * 128;
  const int sw = (fr & 7);

  auto compute = [&](int bufO) {
#pragma unroll
    for (int kk = 0; kk < 2; ++kk) {
      const int ch = (((kk << 2) + kg) ^ sw) * 16;
      short8 ah[2], al[2], bh[2], bl[2];
      ah[0] = *(const short8*)(sm + bufO + rowA0 + ch);
      ah[1] = *(const short8*)(sm + bufO + rowA1 + ch);
      al[0] = *(const short8*)(sm + bufO + 8192 + rowA0 + ch);
      al[1] = *(const short8*)(sm + bufO + 8192 + rowA1 + ch);
      bh[0] = *(const short8*)(sm + bufO + 16384 + rowB0 + ch);
      bh[1] = *(const short8*)(sm + bufO + 16384 + rowB1 + ch);
      bl[0] = *(const short8*)(sm + bufO + 32768 + rowB0 + ch);
      bl[1] = *(const short8*)(sm + bufO + 32768 + rowB1 + ch);
#pragma unroll
      for (int m = 0; m < 2; ++m)
#pragma unroll
        for (int n = 0; n < 2; ++n) {
          acc[m][n] = MFMA16(ah[m], bh[n], acc[m][n]);
          acc[m][n] = MFMA16(ah[m], bl[n], acc[m][n]);
          acc[m][n] = MFMA16(al[m], bh[n], acc[m][n]);
          acc[m][n] = MFMA16(al[m], bl[n], acc[m][n]);
        }
    }
  };

  // ---- prologue: stage K-tile 0 into buffer 0 ----
  stageB(0, 0);
  {
    f32x4 a0 = *reinterpret_cast<const f32x4*>(gA);
    f32x4 a1 = *reinterpret_cast<const f32x4*>(gA + 4);
    short8 h8, l8;
    cvt8(a0, a1, h8, l8);
    *reinterpret_cast<short8*>(sm + wAoff) = h8;
    *reinterpret_cast<short8*>(sm + 8192 + wAoff) = l8;
  }
  __syncthreads();

  // ---- main loop: compute cur, prefetch nxt; 1 barrier per K-tile ----
  for (int kt = 0; kt < 64; ++kt) {
    const int bufO = (kt & 1) * 49152;
    const int nxtO = bufO ^ 49152;
    f32x4 a0, a1;
    const bool pref = (kt < 63);
    if (pref) {
      stageB(nxtO, kt + 1);                         // async L2->LDS for B
      a0 = *reinterpret_cast<const f32x4*>(gA + (kt + 1) * 64);
      a1 = *reinterpret_cast<const f32x4*>(gA + (kt + 1) * 64 + 4);
    }
    compute(bufO);                                  // overlaps staging latency
    if (pref) {
      short8 h8, l8;
      cvt8(a0, a1, h8, l8);
      *reinterpret_cast<short8*>(sm + nxtO + wAoff) = h8;
      *reinterpret_cast<short8*>(sm + nxtO + 8192 + wAoff) = l8;
    }
    __syncthreads();                                // drains vmcnt+lgkm
  }

  // ---- epilogue: bias, gate tile -> LDS (stride 132 f32, conflict-benign) ----
  float* gs = (float*)sm;
  const float bcol0 = bias[wcol * 32 + fr];
  const float bcol1 = bias[wcol * 32 + 16 + fr];
#pragma unroll
  for (int m = 0; m < 2; ++m)
#pragma unroll
    for (int n = 0; n < 2; ++n) {
      const float bc = n ? bcol1 : bcol0;
#pragma unroll
      for (int j = 0; j < 4; ++j) {
        int rr = wrow * 32 + m * 16 + kg * 4 + j;   // C/D: row=(lane>>4)*4+j
        int cc = wcol * 32 + n * 16 + fr;           //      col=lane&15
        gs[rr * 132 + cc] = acc[m][n][j] + bc;
      }
    }
  __syncthreads();

  // ---- top-2 + softmax: 8 lanes per row, strided scan, shfl_xor merge ----
  const int row = wv * 8 + (lane >> 3);
  const int sub = lane & 7;
  float v1 = -3.0e38f, v2 = -3.0e38f;
  int i1 = 1 << 30, i2 = 1 << 30;
#pragma unroll
  for (int i = 0; i < 16; ++i) {
    int e = sub + 8 * i;                            // conflict-free banks
    float v = gs[row * 132 + e];
    if (v > v1 || (v == v1 && e < i1)) { v2 = v1; i2 = i1; v1 = v; i1 = e; }
    else if (v > v2 || (v == v2 && e < i2)) { v2 = v; i2 = e; }
  }
#pragma unroll
  for (int off = 1; off < 8; off <<= 1) {
    float pv1 = __shfl_xor(v1, off); int pi1 = __shfl_xor(i1, off);
    float pv2 = __shfl_xor(v2, off); int pi2 = __shfl_xor(i2, off);
    merge2(v1, i1, v2, i2, pv1, pi1, pv2, pi2);
  }
  // all 8 lanes now agree on (v1,i1,v2,i2); compute v3 = max excluding {i1,i2}
  float v3 = -3.0e38f;
#pragma unroll
  for (int i = 0; i < 16; ++i) {
    int e = sub + 8 * i;
    float v = gs[row * 132 + e];
    if (e != i1 && e != i2) v3 = fmaxf(v3, v);
  }
#pragma unroll
  for (int off = 1; off < 8; off <<= 1) v3 = fmaxf(v3, __shfl_xor(v3, off));

  if (sub == 0) {
    int gr = rb + row;
    float d = expf(v2 - v1);                        // v1 >= v2 -> stable
    float inv = 1.0f / (1.0f + d);
    out[gr * 2 + 0] = (float)i1;                    // indices as float values
    out[gr * 2 + 1] = (float)i2;
    out[2 * N_TOK + gr * 2 + 0] = inv;              // softmax scores
    out[2 * N_TOK + gr * 2 + 1] = d * inv;
    flags[gr] = ((v1 - v2 < GAP_THR) || (v2 - v3 < GAP_THR)) ? 1u : 0u;
  }
}

// ---- Kernel 3: exact fp32 re-score for flagged rows -----------------------
// grid 256 x 64 rows. Non-flagged rows cost one cached flag read. Flagged:
// 256 threads = 2 per expert, exact fp32 dot, block top-2, overwrite outputs.
__global__ __launch_bounds__(256) void fixup_kernel(const float* __restrict__ A,
                                                    const float* __restrict__ W,
                                                    const float* __restrict__ bias,
                                                    const unsigned int* __restrict__ flags,
                                                    float* __restrict__ out) {
  __shared__ unsigned int fl[64];
  __shared__ float sg[128];
  const int tid = threadIdx.x;
  const int rbase = blockIdx.x * 64;
  if (tid < 64) fl[tid] = flags[rbase + tid];
  __syncthreads();
  for (int r = 0; r < 64; ++r) {
    if (fl[r] == 0) continue;                       // uniform branch
    const int row = rbase + r;
    const int e = tid >> 1, h = tid & 1;
    const float* a = A + (size_t)row * N_DIM + h * 2048;
    const float* w = W + (size_t)e * N_DIM + h * 2048;
    float s0 = 0.f, s1 = 0.f, s2 = 0.f, s3 = 0.f;
    for (int k = 0; k < 2048; k += 8) {
      f32x4 av0 = *(const f32x4*)(a + k);
      f32x4 av1 = *(const f32x4*)(a + k + 4);
      f32x4 wv0 = *(const f32x4*)(w + k);
      f32x4 wv1 = *(const f32x4*)(w + k + 4);
      s0 += av0[0] * wv0[0] + av0[1] * wv0[1];
      s1 += av0[2] * wv0[2] + av0[3] * wv0[3];
      s2 += av1[0] * wv1[0] + av1[1] * wv1[1];
      s3 += av1[2] * wv1[2] + av1[3] * wv1[3];
    }
    float s = (s0 + s1) + (s2 + s3);
    s += __shfl_xor(s, 1);                          // partner lane (same expert)
    if (h == 0) sg[e] = s + bias[e];
    __syncthreads();
    if (tid < 64) {                                 // wave 0 merges 128 experts
      float va = sg[tid], vb = sg[tid + 64];
      float v1, v2; int i1, i2;
      if (vb > va) { v1 = vb; i1 = tid + 64; v2 = va; i2 = tid; }
      else         { v1 = va; i1 = tid;      v2 = vb; i2 = tid + 64; }
#pragma unroll
      for (int off = 1; off < 64; off <<= 1) {
        float pv1 = __shfl_xor(v1, off); int pi1 = __shfl_xor(i1, off);
        float pv2 = __shfl_xor(v2, off); int pi2 = __shfl_xor(i2, off);
        merge2(v1, i1, v2, i2, pv1, pi1, pv2, pi2);
      }
      if (tid == 0) {
        float d = expf(v2 - v1);
        float inv = 1.0f / (1.0f + d);
        out[row * 2 + 0] = (float)i1;
        out[row * 2 + 1] = (float)i2;
        out[2 * N_TOK + row * 2 + 0] = inv;
        out[2 * N_TOK + row * 2 + 1] = d * inv;
      }
    }
    __syncthreads();
  }
}

extern "C" void kernel_launch(void* const* d_in, const int* in_sizes, int n_in,
                              void* d_out, int out_size, void* d_ws, size_t ws_size,
                              hipStream_t stream) {
  const float* inp = (const float*)d_in[0];   // [16384*4096]
  const float* W   = (const float*)d_in[1];   // [128*4096]
  const float* b   = (const float*)d_in[2];   // [128]
  float* out = (float*)d_out;                 // [32768 idx][32768 score]

  unsigned short* Whi = (unsigned short*)d_ws;                  // 1 MB
  unsigned short* Wlo = Whi + N_EXP * N_DIM;                    // 1 MB
  unsigned int* flags = (unsigned int*)((char*)d_ws + 2 * N_EXP * N_DIM * 2); // 64 KB

  wsplit_kernel<<<256, 256, 0, stream>>>(W, Whi, Wlo);
  gate_topk_kernel<<<256, 512, 98304, stream>>>(inp, Whi, Wlo, b, out, flags);
  fixup_kernel<<<256, 256, 0, stream>>>(inp, W, b, flags, out);
}

// Round 5
// 486.195 us; speedup vs baseline: 1.6448x; 1.6448x over previous
//
#include <hip/hip_runtime.h>
#include <hip/hip_bf16.h>
#include <stdint.h>

// FMoENaiveGate on MI355X (gfx950).
// gate = inp[16384,4096] @ W[128,4096]^T + b ; top-2 + softmax, fused.
// fp32 via 4-product bf16 hi/lo split MFMA; rows with top-3 gaps < 1e-3 are
// appended to a compact list and re-scored exactly in fp32 by fixup_kernel.
// Gate main loop: 3-deep ring pipeline, counted vmcnt (never 0), raw barrier.

typedef __attribute__((ext_vector_type(8))) short  short8;   // bf16x8 frag
typedef __attribute__((ext_vector_type(4))) float  f32x4;

typedef __attribute__((address_space(1))) unsigned int GU;   // global
typedef __attribute__((address_space(3))) unsigned int LU;   // LDS

#define MFMA16(a, b, c) __builtin_amdgcn_mfma_f32_16x16x32_bf16((a), (b), (c), 0, 0, 0)

#define N_TOK 16384
#define N_DIM 4096
#define N_EXP 128
#define GAP_THR 1.0e-3f
#define FIX_GRID 2048
#define BUF_SZ 49152   // one ring buffer: A_hi 8K | A_lo 8K | B_hi 16K | B_lo 16K

#define VMCNT4() asm volatile("s_waitcnt vmcnt(4)" ::: "memory")
#define VMCNT0() asm volatile("s_waitcnt vmcnt(0)" ::: "memory")
#define LGKM0()  asm volatile("s_waitcnt lgkmcnt(0)" ::: "memory")

// ---- fp32 -> bf16 RNE, and hi/lo split ------------------------------------
__device__ __forceinline__ unsigned short f2bf(float f) {
  uint32_t u = __float_as_uint(f);
  u += 0x7fffu + ((u >> 16) & 1u);          // round-nearest-even
  return (unsigned short)(u >> 16);
}
__device__ __forceinline__ void split2(float x, short& h, short& l) {
  unsigned short hb = f2bf(x);
  float hf = __uint_as_float(((uint32_t)hb) << 16);
  l = (short)f2bf(x - hf);                  // x - hf exact (Sterbenz)
  h = (short)hb;
}
__device__ __forceinline__ void cvt8(const f32x4& a, const f32x4& b, short8& h8, short8& l8) {
#pragma unroll
  for (int i = 0; i < 4; ++i) { short h, l; split2(a[i], h, l); h8[i] = h; l8[i] = l; }
#pragma unroll
  for (int i = 0; i < 4; ++i) { short h, l; split2(b[i], h, l); h8[4 + i] = h; l8[4 + i] = l; }
}

// top-2 merge, jax.lax.top_k tie rule (lower index wins on equal value)
__device__ __forceinline__ void merge2(float& v1, int& i1, float& v2, int& i2,
                                       float pv1, int pi1, float pv2, int pi2) {
  if (pv1 > v1 || (pv1 == v1 && pi1 < i1)) { v2 = v1; i2 = i1; v1 = pv1; i1 = pi1; }
  else if (pv1 > v2 || (pv1 == v2 && pi1 < i2)) { v2 = pv1; i2 = pi1; }
  if (pv2 > v1 || (pv2 == v1 && pi2 < i1)) { v2 = v1; i2 = i1; v1 = pv2; i1 = pi2; }
  else if (pv2 > v2 || (pv2 == v2 && pi2 < i2)) { v2 = pv2; i2 = pi2; }
}

// ---- Kernel 0: zero the compaction counter --------------------------------
__global__ __launch_bounds__(64) void zero_kernel(unsigned int* __restrict__ cnt) {
  if (threadIdx.x == 0) cnt[0] = 0u;
}

// ---- Kernel 1: W [128][4096] f32 -> Whi/Wlo bf16 --------------------------
__global__ __launch_bounds__(256) void wsplit_kernel(const float* __restrict__ W,
                                                     unsigned short* __restrict__ Whi,
                                                     unsigned short* __restrict__ Wlo) {
  int g = blockIdx.x * 256 + threadIdx.x;
  int base = g * 8;
  f32x4 v0 = *reinterpret_cast<const f32x4*>(W + base);
  f32x4 v1 = *reinterpret_cast<const f32x4*>(W + base + 4);
  short8 h8, l8;
  cvt8(v0, v1, h8, l8);
  *reinterpret_cast<short8*>(Whi + base) = h8;
  *reinterpret_cast<short8*>(Wlo + base) = l8;
}

// ---- Kernel 2: fused split-GEMM + bias + top2 + softmax + flag-compact ----
// BM=64, BN=128, BK=64. 512 thr / 8 waves (2Mx4N), wave tile 32x32.
// Ring of 3 buffers x 48KB = 144KB dynamic LDS; 1 block/CU.
// Pipeline invariant: at top of iter t, outstanding vmem = [B(t+1)x4, A(t+1)x2];
// after stageB(t+2) it is 10; vmcnt(4) retires exactly B(t+1)+A(t+1) and keeps
// B(t+2) in flight. No vmcnt(0) until the tail (t=62).
__global__ __launch_bounds__(512) void gate_topk_kernel(const float* __restrict__ A,
                                                        const unsigned short* __restrict__ Whi,
                                                        const unsigned short* __restrict__ Wlo,
                                                        const float* __restrict__ bias,
                                                        float* __restrict__ out,
                                                        unsigned int* __restrict__ cnt,
                                                        int* __restrict__ list) {
  extern __shared__ char sm[];
  const int tid  = threadIdx.x;
  const int lane = tid & 63;
  const int wv   = tid >> 6;        // 0..7
  const int wrow = wv >> 2;         // 0..1  (M)
  const int wcol = wv & 3;          // 0..3  (N)
  const int fr   = lane & 15;
  const int kg   = lane >> 4;       // 0..3
  const int rb   = blockIdx.x * 64; // grid = 256

  f32x4 acc[2][2];
#pragma unroll
  for (int m = 0; m < 2; ++m)
#pragma unroll
    for (int n = 0; n < 2; ++n) acc[m][n] = (f32x4){0.f, 0.f, 0.f, 0.f};

  // A staging: thread owns row rA, 8 fp32 at col cA*8 per K-tile
  const int rA = tid >> 3, cA = tid & 7;
  const float* gA = A + (size_t)(rb + rA) * N_DIM + cA * 8;
  const int wAoff = rA * 128 + ((cA ^ (rA & 7)) * 16);   // swizzled 16B chunk

  // B staging: linear LDS dest (glds requirement) + inverse-swizzled source
  int sBoff[2];
#pragma unroll
  for (int p = 0; p < 2; ++p) {
    int s = p * 512 + tid;
    int rW = s >> 3, pc = s & 7;
    sBoff[p] = rW * N_DIM + ((pc ^ (rW & 7)) * 8);       // elements
  }

  auto stageB = [&](int ofs, int ktn) {
#pragma unroll
    for (int p = 0; p < 2; ++p) {
      const unsigned short* gh = Whi + sBoff[p] + ktn * 64;
      const unsigned short* gl = Wlo + sBoff[p] + ktn * 64;
      char* lbh = sm + ofs + 16384 + (p * 512 + wv * 64) * 16;  // wave-uniform
      char* lbl = sm + ofs + 32768 + (p * 512 + wv * 64) * 16;
      __builtin_amdgcn_global_load_lds((const GU*)gh, (LU*)lbh, 16, 0, 0);
      __builtin_amdgcn_global_load_lds((const GU*)gl, (LU*)lbl, 16, 0, 0);
    }
  };

  const int rowA0 = (wrow * 32 + fr) * 128;
  const int rowA1 = rowA0 + 16 * 128;
  const int rowB0 = (wcol * 32 + fr) * 128;
  const int rowB1 = rowB0 + 16 * 128;
  const int sw = (fr & 7);

  auto compute = [&](int ofs) {
#pragma unroll
    for (int kk = 0; kk < 2; ++kk) {
      const int ch = (((kk << 2) + kg) ^ sw) * 16;
      short8 ah[2], al[2], bh[2], bl[2];
      ah[0] = *(const short8*)(sm + ofs + rowA0 + ch);
      ah[1] = *(const short8*)(sm + ofs + rowA1 + ch);
      al[0] = *(const short8*)(sm + ofs + 8192 + rowA0 + ch);
      al[1] = *(const short8*)(sm + ofs + 8192 + rowA1 + ch);
      bh[0] = *(const short8*)(sm + ofs + 16384 + rowB0 + ch);
      bh[1] = *(const short8*)(sm + ofs + 16384 + rowB1 + ch);
      bl[0] = *(const short8*)(sm + ofs + 32768 + rowB0 + ch);
      bl[1] = *(const short8*)(sm + ofs + 32768 + rowB1 + ch);
#pragma unroll
      for (int m = 0; m < 2; ++m)
#pragma unroll
        for (int n = 0; n < 2; ++n) {
          acc[m][n] = MFMA16(ah[m], bh[n], acc[m][n]);
          acc[m][n] = MFMA16(ah[m], bl[n], acc[m][n]);
          acc[m][n] = MFMA16(al[m], bh[n], acc[m][n]);
          acc[m][n] = MFMA16(al[m], bl[n], acc[m][n]);
        }
    }
  };

  // ---- prologue: B0,A0,B1 issued; A0 -> buf0; A1 issued ----
  f32x4 a0, a1;
  stageB(0, 0);
  a0 = *reinterpret_cast<const f32x4*>(gA);
  a1 = *reinterpret_cast<const f32x4*>(gA + 4);
  stageB(BUF_SZ, 1);
  VMCNT4();                                       // A0 (and B0) done; B1 in flight
  {
    short8 h8, l8;
    cvt8(a0, a1, h8, l8);
    *reinterpret_cast<short8*>(sm + wAoff) = h8;
    *reinterpret_cast<short8*>(sm + 8192 + wAoff) = l8;
  }
  a0 = *reinterpret_cast<const f32x4*>(gA + 64);  // A1
  a1 = *reinterpret_cast<const f32x4*>(gA + 64 + 4);
  LGKM0();
  __builtin_amdgcn_s_barrier();

  // ---- main loop: steady state has [B(t+1), A(t+1), B(t+2)] in flight ----
  int oR = 0, oW = BUF_SZ, oG = 2 * BUF_SZ;
  for (int t = 0; t < 64; ++t) {
    if (t < 62) stageB(oG, t + 2);                // 4 glds -> buf (t+2)%3
    if (t < 63) {
      if (t < 62) { VMCNT4(); } else { VMCNT0(); }  // A(t+1) regs + B(t+1) LDS done
      short8 h8, l8;
      cvt8(a0, a1, h8, l8);
      *reinterpret_cast<short8*>(sm + oW + wAoff) = h8;
      *reinterpret_cast<short8*>(sm + oW + 8192 + wAoff) = l8;
      if (t < 62) {                               // issue A(t+2) into freed slot
        a0 = *reinterpret_cast<const f32x4*>(gA + (t + 2) * 64);
        a1 = *reinterpret_cast<const f32x4*>(gA + (t + 2) * 64 + 4);
      }
    }
    __builtin_amdgcn_s_setprio(1);
    compute(oR);
    __builtin_amdgcn_s_setprio(0);
    LGKM0();                                      // own ds_writes/reads drained
    __builtin_amdgcn_s_barrier();                 // NO vmcnt(0) here (counted pipe)
    int tmp = oR; oR = oW; oW = oG; oG = tmp;     // rotate ring
  }

  // ---- epilogue: bias, gate tile -> LDS (stride 132 f32) ----
  float* gs = (float*)sm;
  const float bcol0 = bias[wcol * 32 + fr];
  const float bcol1 = bias[wcol * 32 + 16 + fr];
#pragma unroll
  for (int m = 0; m < 2; ++m)
#pragma unroll
    for (int n = 0; n < 2; ++n) {
      const float bc = n ? bcol1 : bcol0;
#pragma unroll
      for (int j = 0; j < 4; ++j) {
        int rr = wrow * 32 + m * 16 + kg * 4 + j;   // C/D: row=(lane>>4)*4+j
        int cc = wcol * 32 + n * 16 + fr;           //      col=lane&15
        gs[rr * 132 + cc] = acc[m][n][j] + bc;
      }
    }
  __syncthreads();

  // ---- top-2 + softmax: 8 lanes per row ----
  const int row = wv * 8 + (lane >> 3);
  const int sub = lane & 7;
  float v1 = -3.0e38f, v2 = -3.0e38f;
  int i1 = 1 << 30, i2 = 1 << 30;
#pragma unroll
  for (int i = 0; i < 16; ++i) {
    int e = sub + 8 * i;
    float v = gs[row * 132 + e];
    if (v > v1 || (v == v1 && e < i1)) { v2 = v1; i2 = i1; v1 = v; i1 = e; }
    else if (v > v2 || (v == v2 && e < i2)) { v2 = v; i2 = e; }
  }
#pragma unroll
  for (int off = 1; off < 8; off <<= 1) {
    float pv1 = __shfl_xor(v1, off); int pi1 = __shfl_xor(i1, off);
    float pv2 = __shfl_xor(v2, off); int pi2 = __shfl_xor(i2, off);
    merge2(v1, i1, v2, i2, pv1, pi1, pv2, pi2);
  }
  float v3 = -3.0e38f;
#pragma unroll
  for (int i = 0; i < 16; ++i) {
    int e = sub + 8 * i;
    float v = gs[row * 132 + e];
    if (e != i1 && e != i2) v3 = fmaxf(v3, v);
  }
#pragma unroll
  for (int off = 1; off < 8; off <<= 1) v3 = fmaxf(v3, __shfl_xor(v3, off));

  if (sub == 0) {
    int gr = rb + row;
    float d = expf(v2 - v1);
    float inv = 1.0f / (1.0f + d);
    out[gr * 2 + 0] = (float)i1;
    out[gr * 2 + 1] = (float)i2;
    out[2 * N_TOK + gr * 2 + 0] = inv;
    out[2 * N_TOK + gr * 2 + 1] = d * inv;
    if ((v1 - v2 < GAP_THR) || (v2 - v3 < GAP_THR)) {
      unsigned int slot = atomicAdd(cnt, 1u);     // device-scope, cross-XCD safe
      list[slot] = gr;
    }
  }
}

// ---- Kernel 3: exact fp32 re-score, one flagged row per block -------------
__global__ __launch_bounds__(256) void fixup_kernel(const float* __restrict__ A,
                                                    const float* __restrict__ W,
                                                    const float* __restrict__ bias,
                                                    const unsigned int* __restrict__ cnt,
                                                    const int* __restrict__ list,
                                                    float* __restrict__ out) {
  __shared__ float sg[128];
  const int tid = threadIdx.x;
  int n = (int)cnt[0];
  n = n < N_TOK ? n : N_TOK;                      // defensive clamp
  for (int j = blockIdx.x; j < n; j += FIX_GRID) {
    const int row = list[j];
    const int e = tid >> 1, h = tid & 1;
    const float* a = A + (size_t)row * N_DIM + h * 2048;
    const float* w = W + (size_t)e * N_DIM + h * 2048;
    float s0 = 0.f, s1 = 0.f, s2 = 0.f, s3 = 0.f;
#pragma unroll 4
    for (int k = 0; k < 2048; k += 8) {
      f32x4 av0 = *(const f32x4*)(a + k);
      f32x4 av1 = *(const f32x4*)(a + k + 4);
      f32x4 wv0 = *(const f32x4*)(w + k);
      f32x4 wv1 = *(const f32x4*)(w + k + 4);
      s0 += av0[0] * wv0[0] + av0[1] * wv0[1];
      s1 += av0[2] * wv0[2] + av0[3] * wv0[3];
      s2 += av1[0] * wv1[0] + av1[1] * wv1[1];
      s3 += av1[2] * wv1[2] + av1[3] * wv1[3];
    }
    float s = (s0 + s1) + (s2 + s3);
    s += __shfl_xor(s, 1);                        // partner lane, same expert
    if (h == 0) sg[e] = s + bias[e];
    __syncthreads();
    if (tid < 64) {                               // wave 0 merges 128 experts
      float va = sg[tid], vb = sg[tid + 64];
      float v1, v2; int i1, i2;
      if (vb > va) { v1 = vb; i1 = tid + 64; v2 = va; i2 = tid; }
      else         { v1 = va; i1 = tid;      v2 = vb; i2 = tid + 64; }
#pragma unroll
      for (int off = 1; off < 64; off <<= 1) {
        float pv1 = __shfl_xor(v1, off); int pi1 = __shfl_xor(i1, off);
        float pv2 = __shfl_xor(v2, off); int pi2 = __shfl_xor(i2, off);
        merge2(v1, i1, v2, i2, pv1, pi1, pv2, pi2);
      }
      if (tid == 0) {
        float d = expf(v2 - v1);
        float inv = 1.0f / (1.0f + d);
        out[row * 2 + 0] = (float)i1;
        out[row * 2 + 1] = (float)i2;
        out[2 * N_TOK + row * 2 + 0] = inv;
        out[2 * N_TOK + row * 2 + 1] = d * inv;
      }
    }
    __syncthreads();                              // sg reuse guard for next j
  }
}

extern "C" void kernel_launch(void* const* d_in, const int* in_sizes, int n_in,
                              void* d_out, int out_size, void* d_ws, size_t ws_size,
                              hipStream_t stream) {
  const float* inp = (const float*)d_in[0];   // [16384*4096]
  const float* W   = (const float*)d_in[1];   // [128*4096]
  const float* b   = (const float*)d_in[2];   // [128]
  float* out = (float*)d_out;                 // [32768 idx][32768 score]

  unsigned short* Whi = (unsigned short*)d_ws;                        // 1 MB
  unsigned short* Wlo = Whi + N_EXP * N_DIM;                          // 1 MB
  char* wsb = (char*)d_ws + (size_t)2 * N_EXP * N_DIM * 2;
  unsigned int* cnt = (unsigned int*)wsb;                             // 4 B (pad 256)
  int* list = (int*)(wsb + 256);                                      // 64 KB

  zero_kernel<<<1, 64, 0, stream>>>(cnt);
  wsplit_kernel<<<256, 256, 0, stream>>>(W, Whi, Wlo);
  gate_topk_kernel<<<256, 512, 3 * BUF_SZ, stream>>>(inp, Whi, Wlo, b, out, cnt, list);
  fixup_kernel<<<FIX_GRID, 256, 0, stream>>>(inp, W, b, cnt, list, out);
}